// Round 1
// baseline (707.997 us; speedup 1.0000x reference)
//
#include <hip/hip_runtime.h>

typedef _Float16 f16;
typedef _Float16 f16x2 __attribute__((ext_vector_type(2)));
typedef _Float16 f16x8 __attribute__((ext_vector_type(8)));
typedef short    s16x2 __attribute__((ext_vector_type(2)));

#define LOG2E_X2 2.8853900817779268f   // 2*log2(e)

#if __has_builtin(__builtin_elementwise_fma)
#define FMA2(a,b,c) __builtin_elementwise_fma((a),(b),(c))
#else
#define FMA2(a,b,c) ((a)*(b)+(c))
#endif

static __device__ __forceinline__ float fdot2f(f16x2 a, f16x2 b, float c) {
#if __has_builtin(__builtin_amdgcn_fdot2)
  return __builtin_amdgcn_fdot2(a, b, c, false);
#else
  return c + (float)a[0] * (float)b[0] + (float)a[1] * (float)b[1];
#endif
}

// ---------------- kernel 0: q -> f16 copy + Qsum ----------------
__global__ void k_qprep(const float* __restrict__ q, f16* __restrict__ qh,
                        float* __restrict__ qsum) {
  const int t = threadIdx.x;  // 512 threads
  float v = q[t];
  qh[t] = (f16)v;
  float s = v;
#pragma unroll
  for (int o = 1; o < 64; o <<= 1) s += __shfl_xor(s, o);
  __shared__ float red[8];
  if ((t & 63) == 0) red[t >> 6] = s;
  __syncthreads();
  if (t == 0) {
    float tot = 0.f;
#pragma unroll
    for (int i = 0; i < 8; ++i) tot += red[i];
    *qsum = tot;
  }
}

// ------- kernel 1: u = X@W^T + b ; e = f16(exp(2*clamp(u,±3.7))/16) -------
// X: [8192,512] f32, W: [512,512], grid (8, 128, 2), 256 thr, 64x64 tile
__global__ __launch_bounds__(256) void k_gemm_exp(
    const float* __restrict__ X, const float* __restrict__ W1,
    const float* __restrict__ b1, const float* __restrict__ W2,
    const float* __restrict__ b2, f16* __restrict__ e1, f16* __restrict__ e2) {
  const int z = blockIdx.z;
  const float* W = z ? W2 : W1;
  const float* bias = z ? b2 : b1;
  f16* out = z ? e2 : e1;
  const int r0 = blockIdx.y * 64;
  const int c0 = blockIdx.x * 64;
  __shared__ alignas(16) float Xs[64][68];
  __shared__ alignas(16) float Ws[64][68];
  const int t = threadIdx.x;
  const int row = t >> 2, seg = t & 3;
  const int tr = t >> 4, tc = t & 15;
  float acc[4][4] = {};
#pragma unroll 1
  for (int k0 = 0; k0 < 512; k0 += 64) {
    const float4* gx = (const float4*)(X + (size_t)(r0 + row) * 512 + k0 + seg * 16);
    float4* lx = (float4*)(&Xs[row][seg * 16]);
    lx[0] = gx[0]; lx[1] = gx[1]; lx[2] = gx[2]; lx[3] = gx[3];
    const float4* gw = (const float4*)(W + (size_t)(c0 + row) * 512 + k0 + seg * 16);
    float4* lw = (float4*)(&Ws[row][seg * 16]);
    lw[0] = gw[0]; lw[1] = gw[1]; lw[2] = gw[2]; lw[3] = gw[3];
    __syncthreads();
#pragma unroll 4
    for (int kk = 0; kk < 64; kk += 4) {
      float4 av[4], bv[4];
#pragma unroll
      for (int ii = 0; ii < 4; ++ii) av[ii] = *(const float4*)&Xs[tr + 16 * ii][kk];
#pragma unroll
      for (int jj = 0; jj < 4; ++jj) bv[jj] = *(const float4*)&Ws[tc + 16 * jj][kk];
#pragma unroll
      for (int ii = 0; ii < 4; ++ii) {
#pragma unroll
        for (int jj = 0; jj < 4; ++jj) {
          acc[ii][jj] = fmaf(av[ii].x, bv[jj].x, acc[ii][jj]);
          acc[ii][jj] = fmaf(av[ii].y, bv[jj].y, acc[ii][jj]);
          acc[ii][jj] = fmaf(av[ii].z, bv[jj].z, acc[ii][jj]);
          acc[ii][jj] = fmaf(av[ii].w, bv[jj].w, acc[ii][jj]);
        }
      }
    }
    __syncthreads();
  }
#pragma unroll
  for (int ii = 0; ii < 4; ++ii) {
    const int r = r0 + tr + 16 * ii;
#pragma unroll
    for (int jj = 0; jj < 4; ++jj) {
      const int c = c0 + tc + 16 * jj;
      float u = acc[ii][jj] + bias[c];
      float val = u * LOG2E_X2 - 4.0f;              // log2(e^{2u}/16)
      val = fminf(6.6759f, fmaxf(-14.6759f, val));  // clamp u to ±3.7 (never active on this data)
      out[(size_t)r * 512 + c] = (f16)exp2f(val);
    }
  }
}

// ------- kernel 2: scores u[b,i,j] = Qsum - (1/128)*sum_h q_h * 256/(E+1) -------
template <int P>
static __device__ __forceinline__ void tanh_dot_step(const f16x8 (&Av)[4],
                                                     const f16x8 (&Bv)[4],
                                                     const f16x8& Qv,
                                                     float (&acc)[4][4]) {
  const f16x2 c256 = {(f16)0.00390625f, (f16)0.00390625f};  // 1/256
  const f16x2 two2 = {(f16)2.0f, (f16)2.0f};
  const s16x2 Kv = {(short)30616, (short)30616};  // rcp magic (±5.1% seed)
  f16x2 qp = __builtin_shufflevector(Qv, Qv, 2 * P, 2 * P + 1);
#pragma unroll
  for (int jj = 0; jj < 4; ++jj) {
    f16x2 bp = __builtin_shufflevector(Bv[jj], Bv[jj], 2 * P, 2 * P + 1);
#pragma unroll
    for (int ii = 0; ii < 4; ++ii) {
      f16x2 ap = __builtin_shufflevector(Av[ii], Av[ii], 2 * P, 2 * P + 1);
      f16x2 d = FMA2(ap, bp, c256);  // (E+1)/256, in [2^-8, ~1e4]
      f16x2 r0 = __builtin_bit_cast(f16x2, Kv - __builtin_bit_cast(s16x2, d));
      f16x2 t1 = FMA2(-d, r0, two2);  // Newton 1
      f16x2 r1 = r0 * t1;
      f16x2 t2 = FMA2(-d, r1, two2);  // Newton 2
      f16x2 r2 = r1 * t2;             // ~1/d, rel err ~1e-3
      acc[ii][jj] = fdot2f(r2, qp, acc[ii][jj]);
    }
  }
}

__global__ __launch_bounds__(256) void k_scores(const f16* __restrict__ e1,
                                                const f16* __restrict__ e2,
                                                const f16* __restrict__ qh,
                                                const float* __restrict__ qsum_p,
                                                float* __restrict__ out_a) {
  const int b = blockIdx.z, it = blockIdx.y, jt = blockIdx.x;
  __shared__ alignas(16) f16 As[64][136];  // +16B pad: stride 272B, conflict-free
  __shared__ alignas(16) f16 Bs[64][136];
  __shared__ alignas(16) f16 Qs[512];
  const int t = threadIdx.x;
  const size_t eA = (size_t)(b * 1024 + it * 64) * 512;
  const size_t eB = (size_t)(b * 1024 + jt * 64) * 512;
  if (t < 64) ((uint4*)Qs)[t] = ((const uint4*)qh)[t];
  const int row = t >> 2, seg = t & 3;
  const int tr = t >> 4, tc = t & 15;
  float acc[4][4] = {};
#pragma unroll 1
  for (int h0 = 0; h0 < 512; h0 += 128) {
    const uint4* ga = (const uint4*)(e1 + eA + (size_t)row * 512 + h0 + seg * 32);
    uint4* la = (uint4*)(&As[row][seg * 32]);
    la[0] = ga[0]; la[1] = ga[1]; la[2] = ga[2]; la[3] = ga[3];
    const uint4* gb = (const uint4*)(e2 + eB + (size_t)row * 512 + h0 + seg * 32);
    uint4* lb = (uint4*)(&Bs[row][seg * 32]);
    lb[0] = gb[0]; lb[1] = gb[1]; lb[2] = gb[2]; lb[3] = gb[3];
    __syncthreads();
#pragma unroll 2
    for (int g = 0; g < 16; ++g) {
      f16x8 Av[4], Bv[4], Qv;
#pragma unroll
      for (int ii = 0; ii < 4; ++ii) Av[ii] = *(const f16x8*)&As[tr + 16 * ii][g * 8];
#pragma unroll
      for (int jj = 0; jj < 4; ++jj) Bv[jj] = *(const f16x8*)&Bs[tc + 16 * jj][g * 8];
      Qv = *(const f16x8*)&Qs[h0 + g * 8];
      tanh_dot_step<0>(Av, Bv, Qv, acc);
      tanh_dot_step<1>(Av, Bv, Qv, acc);
      tanh_dot_step<2>(Av, Bv, Qv, acc);
      tanh_dot_step<3>(Av, Bv, Qv, acc);
    }
    __syncthreads();
  }
  const float qs = *qsum_p;
#pragma unroll
  for (int ii = 0; ii < 4; ++ii) {
    const size_t orow = (size_t)(b * 1024 + it * 64 + tr + 16 * ii) * 1024;
#pragma unroll
    for (int jj = 0; jj < 4; ++jj)
      out_a[orow + jt * 64 + tc + 16 * jj] = qs - acc[ii][jj] * (1.0f / 128.0f);
  }
}

// ---------------- kernel 3: in-place row softmax, rows of 1024 f32 ----------------
__global__ __launch_bounds__(256) void k_softmax(float* __restrict__ a) {
  float* row = a + (size_t)blockIdx.x * 1024;
  const int t = threadIdx.x;
  float4 v = ((const float4*)row)[t];
  float m = fmaxf(fmaxf(v.x, v.y), fmaxf(v.z, v.w));
#pragma unroll
  for (int o = 1; o < 64; o <<= 1) m = fmaxf(m, __shfl_xor(m, o));
  __shared__ float red[4];
  const int w = t >> 6, ln = t & 63;
  if (ln == 0) red[w] = m;
  __syncthreads();
  m = fmaxf(fmaxf(red[0], red[1]), fmaxf(red[2], red[3]));
  v.x = __expf(v.x - m); v.y = __expf(v.y - m);
  v.z = __expf(v.z - m); v.w = __expf(v.w - m);
  float s = v.x + v.y + v.z + v.w;
#pragma unroll
  for (int o = 1; o < 64; o <<= 1) s += __shfl_xor(s, o);
  __syncthreads();
  if (ln == 0) red[w] = s;
  __syncthreads();
  s = red[0] + red[1] + red[2] + red[3];
  const float inv = 1.0f / s;
  v.x *= inv; v.y *= inv; v.z *= inv; v.w *= inv;
  ((float4*)row)[t] = v;
}

// ---------------- kernel 4: h[b] = a[b] @ X[b]  (1024x1024)@(1024x512) ----------------
__global__ __launch_bounds__(256) void k_av(const float* __restrict__ a,
                                            const float* __restrict__ X,
                                            float* __restrict__ h) {
  const int b = blockIdx.z;
  const int i0 = blockIdx.y * 64;
  const int c0 = blockIdx.x * 64;
  __shared__ alignas(16) float As[64][68];
  __shared__ alignas(16) float Xs[64][68];  // Xs[k][c]
  const float* Ab = a + (size_t)b * 1024 * 1024;
  const float* Xb = X + (size_t)b * 1024 * 512;
  const int t = threadIdx.x;
  const int row = t >> 2, seg = t & 3;
  const int tr = t >> 4, tc = t & 15;
  float acc[4][4] = {};
#pragma unroll 1
  for (int k0 = 0; k0 < 1024; k0 += 64) {
    const float4* ga = (const float4*)(Ab + (size_t)(i0 + row) * 1024 + k0 + seg * 16);
    float4* la = (float4*)(&As[row][seg * 16]);
    la[0] = ga[0]; la[1] = ga[1]; la[2] = ga[2]; la[3] = ga[3];
    const float4* gx = (const float4*)(Xb + (size_t)(k0 + row) * 512 + c0 + seg * 16);
    float4* lx = (float4*)(&Xs[row][seg * 16]);
    lx[0] = gx[0]; lx[1] = gx[1]; lx[2] = gx[2]; lx[3] = gx[3];
    __syncthreads();
#pragma unroll 8
    for (int k = 0; k < 64; ++k) {
      float av[4], bv[4];
#pragma unroll
      for (int ii = 0; ii < 4; ++ii) av[ii] = As[tr + 16 * ii][k];
#pragma unroll
      for (int jj = 0; jj < 4; ++jj) bv[jj] = Xs[k][tc + 16 * jj];
#pragma unroll
      for (int ii = 0; ii < 4; ++ii) {
#pragma unroll
        for (int jj = 0; jj < 4; ++jj)
          acc[ii][jj] = fmaf(av[ii], bv[jj], acc[ii][jj]);
      }
    }
    __syncthreads();
  }
#pragma unroll
  for (int ii = 0; ii < 4; ++ii) {
    const size_t orow = (size_t)b * 1024 * 512 + (size_t)(i0 + tr + 16 * ii) * 512;
#pragma unroll
    for (int jj = 0; jj < 4; ++jj)
      h[orow + c0 + tc + 16 * jj] = acc[ii][jj];
  }
}

extern "C" void kernel_launch(void* const* d_in, const int* in_sizes, int n_in,
                              void* d_out, int out_size, void* d_ws, size_t ws_size,
                              hipStream_t stream) {
  const float* inputs = (const float*)d_in[0];  // [8,1024,512]
  const float* W1 = (const float*)d_in[1];
  const float* b1 = (const float*)d_in[2];
  const float* W2 = (const float*)d_in[3];
  const float* b2 = (const float*)d_in[4];
  const float* q  = (const float*)d_in[5];

  float* out_h = (float*)d_out;           // [8,1024,512]
  float* out_a = out_h + 4194304;         // [8,1024,1024]

  char* ws = (char*)d_ws;
  f16* e1 = (f16*)ws;                      // 8,388,608 B
  f16* e2 = (f16*)(ws + 8388608);          // 8,388,608 B
  f16* qh = (f16*)(ws + 16777216);         // 1,024 B
  float* qsum = (float*)(ws + 16778240);   // 4 B

  k_qprep<<<1, 512, 0, stream>>>(q, qh, qsum);
  k_gemm_exp<<<dim3(8, 128, 2), 256, 0, stream>>>(inputs, W1, b1, W2, b2, e1, e2);
  k_scores<<<dim3(16, 16, 8), 256, 0, stream>>>(e1, e2, qh, qsum, out_a);
  k_softmax<<<8192, 256, 0, stream>>>(out_a);
  k_av<<<dim3(8, 16, 8), 256, 0, stream>>>(out_a, inputs, out_h);
}

// Round 2
// 703.298 us; speedup vs baseline: 1.0067x; 1.0067x over previous
//
#include <hip/hip_runtime.h>

typedef _Float16 f16;
typedef _Float16 f16x2 __attribute__((ext_vector_type(2)));
typedef _Float16 f16x8 __attribute__((ext_vector_type(8)));

#define LOG2E_X2 2.8853900817779268f   // 2*log2(e)

static __device__ __forceinline__ float fdot2f(f16x2 a, f16x2 b, float c) {
#if __has_builtin(__builtin_amdgcn_fdot2)
  return __builtin_amdgcn_fdot2(a, b, c, false);
#else
  return c + (float)a[0] * (float)b[0] + (float)a[1] * (float)b[1];
#endif
}

// ---------------- kernel 0: q -> f16 copy + Qsum ----------------
__global__ void k_qprep(const float* __restrict__ q, f16* __restrict__ qh,
                        float* __restrict__ qsum) {
  const int t = threadIdx.x;  // 512 threads
  float v = q[t];
  qh[t] = (f16)v;
  float s = v;
#pragma unroll
  for (int o = 1; o < 64; o <<= 1) s += __shfl_xor(s, o);
  __shared__ float red[8];
  if ((t & 63) == 0) red[t >> 6] = s;
  __syncthreads();
  if (t == 0) {
    float tot = 0.f;
#pragma unroll
    for (int i = 0; i < 8; ++i) tot += red[i];
    *qsum = tot;
  }
}

// ------- kernel 1: u = X@W^T + b ; e = f16(exp(2*clamp(u,±3.7))/16) -------
__global__ __launch_bounds__(256) void k_gemm_exp(
    const float* __restrict__ X, const float* __restrict__ W1,
    const float* __restrict__ b1, const float* __restrict__ W2,
    const float* __restrict__ b2, f16* __restrict__ e1, f16* __restrict__ e2) {
  const int z = blockIdx.z;
  const float* W = z ? W2 : W1;
  const float* bias = z ? b2 : b1;
  f16* out = z ? e2 : e1;
  const int r0 = blockIdx.y * 64;
  const int c0 = blockIdx.x * 64;
  __shared__ alignas(16) float Xs[64][68];
  __shared__ alignas(16) float Ws[64][68];
  const int t = threadIdx.x;
  const int row = t >> 2, seg = t & 3;
  const int tr = t >> 4, tc = t & 15;
  float acc[4][4] = {};
#pragma unroll 1
  for (int k0 = 0; k0 < 512; k0 += 64) {
    const float4* gx = (const float4*)(X + (size_t)(r0 + row) * 512 + k0 + seg * 16);
    float4* lx = (float4*)(&Xs[row][seg * 16]);
    lx[0] = gx[0]; lx[1] = gx[1]; lx[2] = gx[2]; lx[3] = gx[3];
    const float4* gw = (const float4*)(W + (size_t)(c0 + row) * 512 + k0 + seg * 16);
    float4* lw = (float4*)(&Ws[row][seg * 16]);
    lw[0] = gw[0]; lw[1] = gw[1]; lw[2] = gw[2]; lw[3] = gw[3];
    __syncthreads();
#pragma unroll 4
    for (int kk = 0; kk < 64; kk += 4) {
      float4 av[4], bv[4];
#pragma unroll
      for (int ii = 0; ii < 4; ++ii) av[ii] = *(const float4*)&Xs[tr + 16 * ii][kk];
#pragma unroll
      for (int jj = 0; jj < 4; ++jj) bv[jj] = *(const float4*)&Ws[tc + 16 * jj][kk];
#pragma unroll
      for (int ii = 0; ii < 4; ++ii) {
#pragma unroll
        for (int jj = 0; jj < 4; ++jj) {
          acc[ii][jj] = fmaf(av[ii].x, bv[jj].x, acc[ii][jj]);
          acc[ii][jj] = fmaf(av[ii].y, bv[jj].y, acc[ii][jj]);
          acc[ii][jj] = fmaf(av[ii].z, bv[jj].z, acc[ii][jj]);
          acc[ii][jj] = fmaf(av[ii].w, bv[jj].w, acc[ii][jj]);
        }
      }
    }
    __syncthreads();
  }
#pragma unroll
  for (int ii = 0; ii < 4; ++ii) {
    const int r = r0 + tr + 16 * ii;
#pragma unroll
    for (int jj = 0; jj < 4; ++jj) {
      const int c = c0 + tc + 16 * jj;
      float u = acc[ii][jj] + bias[c];
      float val = u * LOG2E_X2 - 4.0f;              // log2(e^{2u}/16)
      val = fminf(6.6759f, fmaxf(-14.6759f, val));  // clamp u to ±3.7
      out[(size_t)r * 512 + c] = (f16)exp2f(val);
    }
  }
}

// ------- kernel 2: u[b,i,j] = Qsum - (1/128)*sum_h q_h * 256/(E+1) -------
// Inner step forced to exactly 7 VALU ops per f16x2 pair via inline asm:
//   v_pk_fma_f16 (d), v_pk_sub_i16 (seed), 2x Newton (pk_fma neg + pk_mul),
//   then v_dot2_f32_f16 accumulate.
template <int P>
static __device__ __forceinline__ void tanh_dot_step(const f16x8 (&Av)[4],
                                                     const f16x8 (&Bv)[4],
                                                     const f16x8& Qv,
                                                     float (&acc)[4][4],
                                                     int c256, int kmag, int two2) {
  f16x2 qp = __builtin_shufflevector(Qv, Qv, 2 * P, 2 * P + 1);
#pragma unroll
  for (int jj = 0; jj < 4; ++jj) {
    f16x2 bp = __builtin_shufflevector(Bv[jj], Bv[jj], 2 * P, 2 * P + 1);
#pragma unroll
    for (int ii = 0; ii < 4; ++ii) {
      f16x2 ap = __builtin_shufflevector(Av[ii], Av[ii], 2 * P, 2 * P + 1);
      f16x2 d, r, t;
      asm("v_pk_fma_f16 %0, %3, %4, %5\n\t"                                  // d=a*b+1/256
          "v_pk_sub_i16 %1, %6, %0\n\t"                                       // r0=K-d (magic)
          "v_pk_fma_f16 %2, %0, %1, %7 neg_lo:[1,0,0] neg_hi:[1,0,0]\n\t"     // t=2-d*r0
          "v_pk_mul_f16 %1, %1, %2\n\t"                                       // r1=r0*t
          "v_pk_fma_f16 %2, %0, %1, %7 neg_lo:[1,0,0] neg_hi:[1,0,0]\n\t"     // t=2-d*r1
          "v_pk_mul_f16 %1, %1, %2"                                           // r2=r1*t
          : "=&v"(d), "=&v"(r), "=&v"(t)
          : "v"(ap), "v"(bp), "v"(c256), "v"(kmag), "v"(two2));
      acc[ii][jj] = fdot2f(r, qp, acc[ii][jj]);
    }
  }
}

__global__ __launch_bounds__(256) void k_scores(const f16* __restrict__ e1,
                                                const f16* __restrict__ e2,
                                                const f16* __restrict__ qh,
                                                const float* __restrict__ qsum_p,
                                                float* __restrict__ out_a) {
  const int b = blockIdx.z, it = blockIdx.y, jt = blockIdx.x;
  __shared__ alignas(16) f16 As[64][72];  // 19.5KB total LDS -> 8 blocks/CU
  __shared__ alignas(16) f16 Bs[64][72];
  __shared__ alignas(16) f16 Qs[512];
  const int t = threadIdx.x;
  const size_t eA = (size_t)(b * 1024 + it * 64) * 512;
  const size_t eB = (size_t)(b * 1024 + jt * 64) * 512;
  if (t < 64) ((uint4*)Qs)[t] = ((const uint4*)qh)[t];
  const int row = t >> 2, seg = t & 3;  // 4 threads/row, 2x uint4 each
  const int tr = t >> 4, tc = t & 15;
  const int c256 = 0x1C001C00;  // f16x2 {1/256, 1/256}
  const int kmag = 0x77987798;  // rcp magic seed
  const int two2 = 0x40004000;  // f16x2 {2, 2}
  float acc[4][4] = {};
#pragma unroll 1
  for (int h0 = 0; h0 < 512; h0 += 64) {
    const f16* gA = e1 + eA + (size_t)row * 512 + h0;
    const f16* gB = e2 + eB + (size_t)row * 512 + h0;
    *(uint4*)(&As[row][seg * 8])      = *(const uint4*)(gA + seg * 8);
    *(uint4*)(&As[row][seg * 8 + 32]) = *(const uint4*)(gA + seg * 8 + 32);
    *(uint4*)(&Bs[row][seg * 8])      = *(const uint4*)(gB + seg * 8);
    *(uint4*)(&Bs[row][seg * 8 + 32]) = *(const uint4*)(gB + seg * 8 + 32);
    __syncthreads();
#pragma unroll 2
    for (int g = 0; g < 8; ++g) {
      f16x8 Av[4], Bv[4], Qv;
#pragma unroll
      for (int ii = 0; ii < 4; ++ii) Av[ii] = *(const f16x8*)&As[tr + 16 * ii][g * 8];
#pragma unroll
      for (int jj = 0; jj < 4; ++jj) Bv[jj] = *(const f16x8*)&Bs[tc + 16 * jj][g * 8];
      Qv = *(const f16x8*)&Qs[h0 + g * 8];
      tanh_dot_step<0>(Av, Bv, Qv, acc, c256, kmag, two2);
      tanh_dot_step<1>(Av, Bv, Qv, acc, c256, kmag, two2);
      tanh_dot_step<2>(Av, Bv, Qv, acc, c256, kmag, two2);
      tanh_dot_step<3>(Av, Bv, Qv, acc, c256, kmag, two2);
    }
    __syncthreads();
  }
  const float qs = *qsum_p;
#pragma unroll
  for (int ii = 0; ii < 4; ++ii) {
    const size_t orow = (size_t)(b * 1024 + it * 64 + tr + 16 * ii) * 1024;
#pragma unroll
    for (int jj = 0; jj < 4; ++jj)
      out_a[orow + jt * 64 + tc + 16 * jj] = qs - acc[ii][jj] * (1.0f / 128.0f);
  }
}

// ---------------- kernel 3: in-place row softmax, rows of 1024 f32 ----------------
__global__ __launch_bounds__(256) void k_softmax(float* __restrict__ a) {
  float* row = a + (size_t)blockIdx.x * 1024;
  const int t = threadIdx.x;
  float4 v = ((const float4*)row)[t];
  float m = fmaxf(fmaxf(v.x, v.y), fmaxf(v.z, v.w));
#pragma unroll
  for (int o = 1; o < 64; o <<= 1) m = fmaxf(m, __shfl_xor(m, o));
  __shared__ float red[4];
  const int w = t >> 6, ln = t & 63;
  if (ln == 0) red[w] = m;
  __syncthreads();
  m = fmaxf(fmaxf(red[0], red[1]), fmaxf(red[2], red[3]));
  v.x = __expf(v.x - m); v.y = __expf(v.y - m);
  v.z = __expf(v.z - m); v.w = __expf(v.w - m);
  float s = v.x + v.y + v.z + v.w;
#pragma unroll
  for (int o = 1; o < 64; o <<= 1) s += __shfl_xor(s, o);
  __syncthreads();
  if (ln == 0) red[w] = s;
  __syncthreads();
  s = red[0] + red[1] + red[2] + red[3];
  const float inv = 1.0f / s;
  v.x *= inv; v.y *= inv; v.z *= inv; v.w *= inv;
  ((float4*)row)[t] = v;
}

// ---------------- kernel 4: h[b] = a[b] @ X[b] ----------------
__global__ __launch_bounds__(256) void k_av(const float* __restrict__ a,
                                            const float* __restrict__ X,
                                            float* __restrict__ h) {
  const int b = blockIdx.z;
  const int i0 = blockIdx.y * 64;
  const int c0 = blockIdx.x * 64;
  __shared__ alignas(16) float As[64][68];
  __shared__ alignas(16) float Xs[64][68];  // Xs[k][c]
  const float* Ab = a + (size_t)b * 1024 * 1024;
  const float* Xb = X + (size_t)b * 1024 * 512;
  const int t = threadIdx.x;
  const int row = t >> 2, seg = t & 3;
  const int tr = t >> 4, tc = t & 15;
  float acc[4][4] = {};
#pragma unroll 1
  for (int k0 = 0; k0 < 1024; k0 += 64) {
    const float4* ga = (const float4*)(Ab + (size_t)(i0 + row) * 1024 + k0 + seg * 16);
    float4* la = (float4*)(&As[row][seg * 16]);
    la[0] = ga[0]; la[1] = ga[1]; la[2] = ga[2]; la[3] = ga[3];
    const float4* gx = (const float4*)(Xb + (size_t)(k0 + row) * 512 + c0 + seg * 16);
    float4* lx = (float4*)(&Xs[row][seg * 16]);
    lx[0] = gx[0]; lx[1] = gx[1]; lx[2] = gx[2]; lx[3] = gx[3];
    __syncthreads();
#pragma unroll 8
    for (int k = 0; k < 64; ++k) {
      float av[4], bv[4];
#pragma unroll
      for (int ii = 0; ii < 4; ++ii) av[ii] = As[tr + 16 * ii][k];
#pragma unroll
      for (int jj = 0; jj < 4; ++jj) bv[jj] = Xs[k][tc + 16 * jj];
#pragma unroll
      for (int ii = 0; ii < 4; ++ii) {
#pragma unroll
        for (int jj = 0; jj < 4; ++jj)
          acc[ii][jj] = fmaf(av[ii], bv[jj], acc[ii][jj]);
      }
    }
    __syncthreads();
  }
#pragma unroll
  for (int ii = 0; ii < 4; ++ii) {
    const size_t orow = (size_t)b * 1024 * 512 + (size_t)(i0 + tr + 16 * ii) * 512;
#pragma unroll
    for (int jj = 0; jj < 4; ++jj)
      h[orow + c0 + tc + 16 * jj] = acc[ii][jj];
  }
}

extern "C" void kernel_launch(void* const* d_in, const int* in_sizes, int n_in,
                              void* d_out, int out_size, void* d_ws, size_t ws_size,
                              hipStream_t stream) {
  const float* inputs = (const float*)d_in[0];  // [8,1024,512]
  const float* W1 = (const float*)d_in[1];
  const float* b1 = (const float*)d_in[2];
  const float* W2 = (const float*)d_in[3];
  const float* b2 = (const float*)d_in[4];
  const float* q  = (const float*)d_in[5];

  float* out_h = (float*)d_out;           // [8,1024,512]
  float* out_a = out_h + 4194304;         // [8,1024,1024]

  char* ws = (char*)d_ws;
  f16* e1 = (f16*)ws;                      // 8,388,608 B
  f16* e2 = (f16*)(ws + 8388608);          // 8,388,608 B
  f16* qh = (f16*)(ws + 16777216);         // 1,024 B
  float* qsum = (float*)(ws + 16778240);   // 4 B

  k_qprep<<<1, 512, 0, stream>>>(q, qh, qsum);
  k_gemm_exp<<<dim3(8, 128, 2), 256, 0, stream>>>(inputs, W1, b1, W2, b2, e1, e2);
  k_scores<<<dim3(16, 16, 8), 256, 0, stream>>>(e1, e2, qh, qsum, out_a);
  k_softmax<<<8192, 256, 0, stream>>>(out_a);
  k_av<<<dim3(8, 16, 8), 256, 0, stream>>>(out_a, inputs, out_h);
}

// Round 3
// 298.639 us; speedup vs baseline: 2.3707x; 2.3550x over previous
//
#include <hip/hip_runtime.h>

typedef _Float16 f16;
typedef _Float16 f16x2 __attribute__((ext_vector_type(2)));
typedef _Float16 f16x4 __attribute__((ext_vector_type(4)));
typedef _Float16 f16x8 __attribute__((ext_vector_type(8)));
typedef float f32x4 __attribute__((ext_vector_type(4)));

#define LOG2E_X2 2.8853900817779268f

// Fourier coefficients: d_m = (2*pi/10)/sinh(pi^2*m/10); tanh(s) ~= 0.2*s + sum d_m sin(0.628319*m*s)
__constant__ float D8[8] = {0.543915f, 0.177997f, 0.0652351f, 0.0242575f,
                            0.00903807f, 0.00336823f, 0.00125536f, 0.000467884f};

static __device__ __forceinline__ void gl2lds16(const void* g, void* l) {
  __builtin_amdgcn_global_load_lds((const __attribute__((address_space(1))) void*)g,
                                   (__attribute__((address_space(3))) void*)l, 16, 0, 0);
}

// ================= new pipeline =================

// X f32 [8,1024,512] -> Xh f16 (same layout) + XhT f16 [8,512,1024]
__global__ __launch_bounds__(256) void k_prep_x(const float* __restrict__ X,
                                                f16* __restrict__ Xh, f16* __restrict__ XhT) {
  const int ht = blockIdx.x, it = blockIdx.y, b = blockIdx.z;
  __shared__ f16 Lt[64][72];
  const int t = threadIdx.x;
  const int r = t >> 4, c4 = (t & 15) * 4;
  const float* Xb = X + ((size_t)b * 1024 + it * 64) * 512 + ht * 64;
#pragma unroll
  for (int k = 0; k < 4; ++k) {
    const int rr = r + 16 * k;
    float4 v = *(const float4*)&Xb[(size_t)rr * 512 + c4];
    f16 h0 = (f16)v.x, h1 = (f16)v.y, h2 = (f16)v.z, h3 = (f16)v.w;
    *(f16x4*)&Xh[((size_t)b * 1024 + it * 64 + rr) * 512 + ht * 64 + c4] = {h0, h1, h2, h3};
    Lt[c4 + 0][rr] = h0; Lt[c4 + 1][rr] = h1; Lt[c4 + 2][rr] = h2; Lt[c4 + 3][rr] = h3;
  }
  __syncthreads();
  const int hr = t >> 2, seg = t & 3;
  f16* dst = &XhT[((size_t)b * 512 + ht * 64 + hr) * 1024 + it * 64 + seg * 16];
  *(f16x8*)(dst) = *(const f16x8*)&Lt[hr][seg * 16];
  *(f16x8*)(dst + 8) = *(const f16x8*)&Lt[hr][seg * 16 + 8];
}

__global__ __launch_bounds__(256) void k_prep_w(const float* __restrict__ W1,
                                                const float* __restrict__ W2,
                                                f16* __restrict__ Wh) {
  const int row = blockIdx.x, z = blockIdx.y, t = threadIdx.x;
  const float* W = z ? W2 : W1;
  float2 v = *(const float2*)&W[(size_t)row * 512 + t * 2];
  *(f16x2*)&Wh[(size_t)z * 262144 + (size_t)row * 512 + t * 2] = {(f16)v.x, (f16)v.y};
}

// trig factor build: A[i, (m,t,h)] = q_h*d_m*{sin,cos}(m*w*a), B = {cos,sin}(m*w*b); also qa,qb row-dots
template <int NM>
__global__ __launch_bounds__(256) void k_trig(const float* __restrict__ u1,
                                              const float* __restrict__ u2,
                                              const float* __restrict__ q,
                                              f16* __restrict__ At, f16* __restrict__ Bt,
                                              float* __restrict__ qa, float* __restrict__ qb,
                                              int m0, int wq) {
  const int i = blockIdx.x, t = threadIdx.x;
  const float w = 0.62831853f;
  const float2 a2 = *(const float2*)&u1[(size_t)i * 512 + 2 * t];
  const float2 b2 = *(const float2*)&u2[(size_t)i * 512 + 2 * t];
  const float2 q2 = *(const float2*)&q[2 * t];
  if (wq) {
    float sa = q2.x * a2.x + q2.y * a2.y;
    float sb = q2.x * b2.x + q2.y * b2.y;
#pragma unroll
    for (int o = 1; o < 64; o <<= 1) { sa += __shfl_xor(sa, o); sb += __shfl_xor(sb, o); }
    __shared__ float red[8];
    const int lane = t & 63, widx = t >> 6;
    if (lane == 0) { red[widx] = sa; red[4 + widx] = sb; }
    __syncthreads();
    if (t == 0) qa[i] = red[0] + red[1] + red[2] + red[3];
    if (t == 1) qb[i] = red[4] + red[5] + red[6] + red[7];
  }
  float s1[4], c1[4], sm_[4], cm_[4];
  const float ang[4] = {w * a2.x, w * a2.y, w * b2.x, w * b2.y};
#pragma unroll
  for (int u = 0; u < 4; ++u) {
    __sincosf(ang[u], &s1[u], &c1[u]);
    if (m0 == 1) { sm_[u] = s1[u]; cm_[u] = c1[u]; }
    else __sincosf(m0 * ang[u], &sm_[u], &cm_[u]);
  }
  const size_t ldT = (size_t)NM * 1024;
  f16* Ar = At + (size_t)i * ldT + 2 * t;
  f16* Br = Bt + (size_t)i * ldT + 2 * t;
#pragma unroll
  for (int j = 0; j < NM; ++j) {
    const float dm = D8[m0 - 1 + j];
    const float qdx = q2.x * dm, qdy = q2.y * dm;
    *(f16x2*)(Ar + j * 1024)       = {(f16)(qdx * sm_[0]), (f16)(qdy * sm_[1])};
    *(f16x2*)(Ar + j * 1024 + 512) = {(f16)(qdx * cm_[0]), (f16)(qdy * cm_[1])};
    *(f16x2*)(Br + j * 1024)       = {(f16)cm_[2], (f16)cm_[3]};
    *(f16x2*)(Br + j * 1024 + 512) = {(f16)sm_[2], (f16)sm_[3]};
    if (j + 1 < NM) {
#pragma unroll
      for (int u = 0; u < 4; ++u) {
        const float ns = sm_[u] * c1[u] + cm_[u] * s1[u];
        const float nc = cm_[u] * c1[u] - sm_[u] * s1[u];
        sm_[u] = ns; cm_[u] = nc;
      }
    }
  }
}

// f16 NT GEMM core, 256x256 tile, BK=64, 512 threads, double-buffered global_load_lds,
// XOR-swizzled LDS. MODE 0: u=Xh@Wh^T+bias; MODE 1: scores partials; MODE 2: h=a16@XhT^T.
template <int MODE, int ACC>
__global__ __launch_bounds__(512, 2) void k_gemm(
    const f16* __restrict__ A, const f16* __restrict__ B, float* __restrict__ C,
    const float* __restrict__ e0, const float* __restrict__ e1,
    int Kloop, int ldAB, long halfA, long halfC) {
  __shared__ alignas(16) char sm[2][2][256 * 64 * 2];  // [buf][side][32KB] = 128KB
  const int t = threadIdx.x;
  const int nx = blockIdx.x, my = blockIdx.y, z = blockIdx.z;
  const f16* Ab; const f16* Bb; float* Cb; const float* bias = nullptr;
  int ldC;
  if (MODE == 0) {
    Ab = A + (size_t)my * 256 * ldAB;
    Bb = B + (size_t)z * 262144 + (size_t)nx * 256 * ldAB;
    Cb = C + (size_t)z * 4194304 + (size_t)my * 256 * 512 + nx * 256;
    bias = (z ? e1 : e0) + nx * 256;
    ldC = 512;
  } else if (MODE == 1) {
    const int b = z & 7, h = z >> 3;
    Ab = A + ((size_t)(b * 1024 + my * 256)) * ldAB + h * halfA;
    Bb = B + ((size_t)(b * 1024 + nx * 256)) * ldAB + h * halfA;
    Cb = C + h * halfC + ((size_t)(b * 1024 + my * 256)) * 1024 + nx * 256;
    ldC = 1024;
  } else {
    Ab = A + ((size_t)(z * 1024 + my * 256)) * ldAB;
    Bb = B + ((size_t)(z * 512 + nx * 256)) * ldAB;
    Cb = C + (size_t)z * 524288 + (size_t)my * 256 * 512 + nx * 256;
    ldC = 512;
  }
  const int wid = t >> 6, lane = t & 63;
  const int wr = wid >> 2, wc = wid & 3;
  const int rl = lane & 15, kc = lane >> 4;
  f32x4 acc[8][4] = {};

  auto stage = [&](int buf, int kt) {
    const f16* gA = Ab + kt * 64;
    const f16* gB = Bb + kt * 64;
    char* lA = sm[buf][0];
    char* lB = sm[buf][1];
#pragma unroll
    for (int ii = 0; ii < 4; ++ii) {
      const int lin = ii * 512 + t;
      const int row = lin >> 3, c = lin & 7;
      const size_t go = (size_t)row * ldAB + ((c ^ (row & 7)) * 8);
      gl2lds16(gA + go, lA + ii * 8192 + wid * 1024);
      gl2lds16(gB + go, lB + ii * 8192 + wid * 1024);
    }
  };

  const int nkt = Kloop >> 6;
  stage(0, 0);
  __syncthreads();
  for (int kt = 0; kt < nkt; ++kt) {
    const int cur = kt & 1;
    if (kt + 1 < nkt) stage(cur ^ 1, kt + 1);
    const char* lA = sm[cur][0];
    const char* lB = sm[cur][1];
#pragma unroll
    for (int kk = 0; kk < 2; ++kk) {
      f16x8 av[8], bv[4];
#pragma unroll
      for (int fi = 0; fi < 8; ++fi) {
        const int rloc = wr * 128 + fi * 16 + rl;
        av[fi] = *(const f16x8*)(lA + rloc * 128 + (((kc + 4 * kk) ^ (rloc & 7)) << 4));
      }
#pragma unroll
      for (int fj = 0; fj < 4; ++fj) {
        const int cloc = wc * 64 + fj * 16 + rl;
        bv[fj] = *(const f16x8*)(lB + cloc * 128 + (((kc + 4 * kk) ^ (cloc & 7)) << 4));
      }
#pragma unroll
      for (int fi = 0; fi < 8; ++fi)
#pragma unroll
        for (int fj = 0; fj < 4; ++fj)
          acc[fi][fj] = __builtin_amdgcn_mfma_f32_16x16x32_f16(av[fi], bv[fj], acc[fi][fj], 0, 0, 0);
    }
    __syncthreads();
  }
#pragma unroll
  for (int fj = 0; fj < 4; ++fj) {
    const int gcol = wc * 64 + fj * 16 + rl;
    const float bvv = (MODE == 0) ? bias[gcol] : 0.f;
#pragma unroll
    for (int fi = 0; fi < 8; ++fi) {
      const int grow0 = wr * 128 + fi * 16 + kc * 4;
      f32x4 v = acc[fi][fj];
#pragma unroll
      for (int r = 0; r < 4; ++r) {
        const size_t o = (size_t)(grow0 + r) * ldC + gcol;
        float x = v[r] + bvv;
        if (ACC) x += Cb[o];
        Cb[o] = x;
      }
    }
  }
}

// softmax over j of u = P0+P1+0.2*(qa_i+qb_j); writes a (f32) and a16 (f16)
__global__ __launch_bounds__(256) void k_softmax2(const float* __restrict__ P0,
                                                  const float* __restrict__ P1,
                                                  const float* __restrict__ qa,
                                                  const float* __restrict__ qb,
                                                  float* __restrict__ out_a,
                                                  f16* __restrict__ a16) {
  const int row = blockIdx.x, t = threadIdx.x;
  const int b = row >> 10;
  const size_t off = (size_t)row * 1024 + t * 4;
  float4 p0 = *(const float4*)(P0 + off);
  float4 p1 = *(const float4*)(P1 + off);
  float4 qb4 = *(const float4*)(qb + (size_t)b * 1024 + t * 4);
  const float qi = qa[row];
  float4 v;
  v.x = p0.x + p1.x + 0.2f * (qi + qb4.x);
  v.y = p0.y + p1.y + 0.2f * (qi + qb4.y);
  v.z = p0.z + p1.z + 0.2f * (qi + qb4.z);
  v.w = p0.w + p1.w + 0.2f * (qi + qb4.w);
  float m = fmaxf(fmaxf(v.x, v.y), fmaxf(v.z, v.w));
#pragma unroll
  for (int o = 1; o < 64; o <<= 1) m = fmaxf(m, __shfl_xor(m, o));
  __shared__ float red[4];
  const int w = t >> 6, ln = t & 63;
  if (ln == 0) red[w] = m;
  __syncthreads();
  m = fmaxf(fmaxf(red[0], red[1]), fmaxf(red[2], red[3]));
  v.x = __expf(v.x - m); v.y = __expf(v.y - m);
  v.z = __expf(v.z - m); v.w = __expf(v.w - m);
  float s = v.x + v.y + v.z + v.w;
#pragma unroll
  for (int o = 1; o < 64; o <<= 1) s += __shfl_xor(s, o);
  __syncthreads();
  if (ln == 0) red[w] = s;
  __syncthreads();
  s = red[0] + red[1] + red[2] + red[3];
  const float inv = 1.0f / s;
  v.x *= inv; v.y *= inv; v.z *= inv; v.w *= inv;
  *(float4*)(out_a + off) = v;
  *(f16x4*)(a16 + off) = {(f16)v.x, (f16)v.y, (f16)v.z, (f16)v.w};
}

// ================= old (fallback) pipeline =================
typedef short s16x2 __attribute__((ext_vector_type(2)));

static __device__ __forceinline__ float fdot2f(f16x2 a, f16x2 b, float c) {
#if __has_builtin(__builtin_amdgcn_fdot2)
  return __builtin_amdgcn_fdot2(a, b, c, false);
#else
  return c + (float)a[0] * (float)b[0] + (float)a[1] * (float)b[1];
#endif
}

__global__ void k_qprep(const float* __restrict__ q, f16* __restrict__ qh,
                        float* __restrict__ qsum) {
  const int t = threadIdx.x;
  float v = q[t];
  qh[t] = (f16)v;
  float s = v;
#pragma unroll
  for (int o = 1; o < 64; o <<= 1) s += __shfl_xor(s, o);
  __shared__ float red[8];
  if ((t & 63) == 0) red[t >> 6] = s;
  __syncthreads();
  if (t == 0) {
    float tot = 0.f;
#pragma unroll
    for (int i = 0; i < 8; ++i) tot += red[i];
    *qsum = tot;
  }
}

__global__ __launch_bounds__(256) void k_gemm_exp(
    const float* __restrict__ X, const float* __restrict__ W1,
    const float* __restrict__ b1, const float* __restrict__ W2,
    const float* __restrict__ b2, f16* __restrict__ e1, f16* __restrict__ e2) {
  const int z = blockIdx.z;
  const float* W = z ? W2 : W1;
  const float* bias = z ? b2 : b1;
  f16* out = z ? e2 : e1;
  const int r0 = blockIdx.y * 64;
  const int c0 = blockIdx.x * 64;
  __shared__ alignas(16) float Xs[64][68];
  __shared__ alignas(16) float Ws[64][68];
  const int t = threadIdx.x;
  const int row = t >> 2, seg = t & 3;
  const int tr = t >> 4, tc = t & 15;
  float acc[4][4] = {};
#pragma unroll 1
  for (int k0 = 0; k0 < 512; k0 += 64) {
    const float4* gx = (const float4*)(X + (size_t)(r0 + row) * 512 + k0 + seg * 16);
    float4* lx = (float4*)(&Xs[row][seg * 16]);
    lx[0] = gx[0]; lx[1] = gx[1]; lx[2] = gx[2]; lx[3] = gx[3];
    const float4* gw = (const float4*)(W + (size_t)(c0 + row) * 512 + k0 + seg * 16);
    float4* lw = (float4*)(&Ws[row][seg * 16]);
    lw[0] = gw[0]; lw[1] = gw[1]; lw[2] = gw[2]; lw[3] = gw[3];
    __syncthreads();
#pragma unroll 4
    for (int kk = 0; kk < 64; kk += 4) {
      float4 av[4], bv[4];
#pragma unroll
      for (int ii = 0; ii < 4; ++ii) av[ii] = *(const float4*)&Xs[tr + 16 * ii][kk];
#pragma unroll
      for (int jj = 0; jj < 4; ++jj) bv[jj] = *(const float4*)&Ws[tc + 16 * jj][kk];
#pragma unroll
      for (int ii = 0; ii < 4; ++ii) {
#pragma unroll
        for (int jj = 0; jj < 4; ++jj) {
          acc[ii][jj] = fmaf(av[ii].x, bv[jj].x, acc[ii][jj]);
          acc[ii][jj] = fmaf(av[ii].y, bv[jj].y, acc[ii][jj]);
          acc[ii][jj] = fmaf(av[ii].z, bv[jj].z, acc[ii][jj]);
          acc[ii][jj] = fmaf(av[ii].w, bv[jj].w, acc[ii][jj]);
        }
      }
    }
    __syncthreads();
  }
#pragma unroll
  for (int ii = 0; ii < 4; ++ii) {
    const int r = r0 + tr + 16 * ii;
#pragma unroll
    for (int jj = 0; jj < 4; ++jj) {
      const int c = c0 + tc + 16 * jj;
      float u = acc[ii][jj] + bias[c];
      float val = u * LOG2E_X2 - 4.0f;
      val = fminf(6.6759f, fmaxf(-14.6759f, val));
      out[(size_t)r * 512 + c] = (f16)exp2f(val);
    }
  }
}

template <int P>
static __device__ __forceinline__ void tanh_dot_step(const f16x8 (&Av)[4],
                                                     const f16x8 (&Bv)[4],
                                                     const f16x8& Qv, float (&acc)[4][4],
                                                     int c256, int kmag, int two2) {
  f16x2 qp = __builtin_shufflevector(Qv, Qv, 2 * P, 2 * P + 1);
#pragma unroll
  for (int jj = 0; jj < 4; ++jj) {
    f16x2 bp = __builtin_shufflevector(Bv[jj], Bv[jj], 2 * P, 2 * P + 1);
#pragma unroll
    for (int ii = 0; ii < 4; ++ii) {
      f16x2 ap = __builtin_shufflevector(Av[ii], Av[ii], 2 * P, 2 * P + 1);
      f16x2 d, r, tt;
      asm("v_pk_fma_f16 %0, %3, %4, %5\n\t"
          "v_pk_sub_i16 %1, %6, %0\n\t"
          "v_pk_fma_f16 %2, %0, %1, %7 neg_lo:[1,0,0] neg_hi:[1,0,0]\n\t"
          "v_pk_mul_f16 %1, %1, %2\n\t"
          "v_pk_fma_f16 %2, %0, %1, %7 neg_lo:[1,0,0] neg_hi:[1,0,0]\n\t"
          "v_pk_mul_f16 %1, %1, %2"
          : "=&v"(d), "=&v"(r), "=&v"(tt)
          : "v"(ap), "v"(bp), "v"(c256), "v"(kmag), "v"(two2));
      acc[ii][jj] = fdot2f(r, qp, acc[ii][jj]);
    }
  }
}

__global__ __launch_bounds__(256) void k_scores(const f16* __restrict__ e1,
                                                const f16* __restrict__ e2,
                                                const f16* __restrict__ qh,
                                                const float* __restrict__ qsum_p,
                                                float* __restrict__ out_a) {
  const int b = blockIdx.z, it = blockIdx.y, jt = blockIdx.x;
  __shared__ alignas(16) f16 As[64][72];
  __shared__ alignas(16) f16 Bs[64][72];
  __shared__ alignas(16) f16 Qs[512];
  const int t = threadIdx.x;
  const size_t eA = (size_t)(b * 1024 + it * 64) * 512;
  const size_t eB = (size_t)(b * 1024 + jt * 64) * 512;
  if (t < 64) ((uint4*)Qs)[t] = ((const uint4*)qh)[t];
  const int row = t >> 2, seg = t & 3;
  const int tr = t >> 4, tc = t & 15;
  const int c256 = 0x1C001C00;
  const int kmag = 0x77987798;
  const int two2 = 0x40004000;
  float acc[4][4] = {};
#pragma unroll 1
  for (int h0 = 0; h0 < 512; h0 += 64) {
    const f16* gA = e1 + eA + (size_t)row * 512 + h0;
    const f16* gB = e2 + eB + (size_t)row * 512 + h0;
    *(uint4*)(&As[row][seg * 8]) = *(const uint4*)(gA + seg * 8);
    *(uint4*)(&As[row][seg * 8 + 32]) = *(const uint4*)(gA + seg * 8 + 32);
    *(uint4*)(&Bs[row][seg * 8]) = *(const uint4*)(gB + seg * 8);
    *(uint4*)(&Bs[row][seg * 8 + 32]) = *(const uint4*)(gB + seg * 8 + 32);
    __syncthreads();
#pragma unroll 2
    for (int g = 0; g < 8; ++g) {
      f16x8 Av[4], Bv[4], Qv;
#pragma unroll
      for (int ii = 0; ii < 4; ++ii) Av[ii] = *(const f16x8*)&As[tr + 16 * ii][g * 8];
#pragma unroll
      for (int jj = 0; jj < 4; ++jj) Bv[jj] = *(const f16x8*)&Bs[tc + 16 * jj][g * 8];
      Qv = *(const f16x8*)&Qs[h0 + g * 8];
      tanh_dot_step<0>(Av, Bv, Qv, acc, c256, kmag, two2);
      tanh_dot_step<1>(Av, Bv, Qv, acc, c256, kmag, two2);
      tanh_dot_step<2>(Av, Bv, Qv, acc, c256, kmag, two2);
      tanh_dot_step<3>(Av, Bv, Qv, acc, c256, kmag, two2);
    }
    __syncthreads();
  }
  const float qs = *qsum_p;
#pragma unroll
  for (int ii = 0; ii < 4; ++ii) {
    const size_t orow = (size_t)(b * 1024 + it * 64 + tr + 16 * ii) * 1024;
#pragma unroll
    for (int jj = 0; jj < 4; ++jj)
      out_a[orow + jt * 64 + tc + 16 * jj] = qs - acc[ii][jj] * (1.0f / 128.0f);
  }
}

__global__ __launch_bounds__(256) void k_softmax(float* __restrict__ a) {
  float* row = a + (size_t)blockIdx.x * 1024;
  const int t = threadIdx.x;
  float4 v = ((const float4*)row)[t];
  float m = fmaxf(fmaxf(v.x, v.y), fmaxf(v.z, v.w));
#pragma unroll
  for (int o = 1; o < 64; o <<= 1) m = fmaxf(m, __shfl_xor(m, o));
  __shared__ float red[4];
  const int w = t >> 6, ln = t & 63;
  if (ln == 0) red[w] = m;
  __syncthreads();
  m = fmaxf(fmaxf(red[0], red[1]), fmaxf(red[2], red[3]));
  v.x = __expf(v.x - m); v.y = __expf(v.y - m);
  v.z = __expf(v.z - m); v.w = __expf(v.w - m);
  float s = v.x + v.y + v.z + v.w;
#pragma unroll
  for (int o = 1; o < 64; o <<= 1) s += __shfl_xor(s, o);
  __syncthreads();
  if (ln == 0) red[w] = s;
  __syncthreads();
  s = red[0] + red[1] + red[2] + red[3];
  const float inv = 1.0f / s;
  v.x *= inv; v.y *= inv; v.z *= inv; v.w *= inv;
  ((float4*)row)[t] = v;
}

__global__ __launch_bounds__(256) void k_av(const float* __restrict__ a,
                                            const float* __restrict__ X,
                                            float* __restrict__ h) {
  const int b = blockIdx.z;
  const int i0 = blockIdx.y * 64;
  const int c0 = blockIdx.x * 64;
  __shared__ alignas(16) float As[64][68];
  __shared__ alignas(16) float Xs[64][68];
  const float* Ab = a + (size_t)b * 1024 * 1024;
  const float* Xb = X + (size_t)b * 1024 * 512;
  const int t = threadIdx.x;
  const int row = t >> 2, seg = t & 3;
  const int tr = t >> 4, tc = t & 15;
  float acc[4][4] = {};
#pragma unroll 1
  for (int k0 = 0; k0 < 1024; k0 += 64) {
    const float4* ga = (const float4*)(Ab + (size_t)(i0 + row) * 1024 + k0 + seg * 16);
    float4* la = (float4*)(&As[row][seg * 16]);
    la[0] = ga[0]; la[1] = ga[1]; la[2] = ga[2]; la[3] = ga[3];
    const float4* gx = (const float4*)(Xb + (size_t)(k0 + row) * 512 + c0 + seg * 16);
    float4* lx = (float4*)(&Xs[row][seg * 16]);
    lx[0] = gx[0]; lx[1] = gx[1]; lx[2] = gx[2]; lx[3] = gx[3];
    __syncthreads();
#pragma unroll 8
    for (int k = 0; k < 64; ++k) {
      float av[4], bv[4];
#pragma unroll
      for (int ii = 0; ii < 4; ++ii) av[ii] = As[tr + 16 * ii][k];
#pragma unroll
      for (int jj = 0; jj < 4; ++jj) bv[jj] = Xs[k][tc + 16 * jj];
#pragma unroll
      for (int ii = 0; ii < 4; ++ii) {
#pragma unroll
        for (int jj = 0; jj < 4; ++jj)
          acc[ii][jj] = fmaf(av[ii], bv[jj], acc[ii][jj]);
      }
    }
    __syncthreads();
  }
#pragma unroll
  for (int ii = 0; ii < 4; ++ii) {
    const size_t orow = (size_t)b * 1024 * 512 + (size_t)(i0 + tr + 16 * ii) * 512;
#pragma unroll
    for (int jj = 0; jj < 4; ++jj)
      h[orow + c0 + tc + 16 * jj] = acc[ii][jj];
  }
}

// ================= host =================
extern "C" void kernel_launch(void* const* d_in, const int* in_sizes, int n_in,
                              void* d_out, int out_size, void* d_ws, size_t ws_size,
                              hipStream_t stream) {
  const float* inputs = (const float*)d_in[0];
  const float* W1 = (const float*)d_in[1];
  const float* b1 = (const float*)d_in[2];
  const float* W2 = (const float*)d_in[3];
  const float* b2 = (const float*)d_in[4];
  const float* q = (const float*)d_in[5];

  float* out_h = (float*)d_out;            // [8,1024,512]
  float* out_a = out_h + 4194304;          // [8,1024,1024]

  const size_t FIXED = 101777408ULL;       // Xh+XhT+Wh+a16+qa+qb+P0+P1
  const size_t PER_M = 33554432ULL;        // A+B trig per m
  if (ws_size < FIXED + PER_M) {
    // fallback: previous verified pipeline (needs only ~17 MB)
    char* ws = (char*)d_ws;
    f16* e1 = (f16*)ws;
    f16* e2 = (f16*)(ws + 8388608);
    f16* qh = (f16*)(ws + 16777216);
    float* qsum = (float*)(ws + 16778240);
    k_qprep<<<1, 512, 0, stream>>>(q, qh, qsum);
    k_gemm_exp<<<dim3(8, 128, 2), 256, 0, stream>>>(inputs, W1, b1, W2, b2, e1, e2);
    k_scores<<<dim3(16, 16, 8), 256, 0, stream>>>(e1, e2, qh, qsum, out_a);
    k_softmax<<<8192, 256, 0, stream>>>(out_a);
    k_av<<<dim3(8, 16, 8), 256, 0, stream>>>(out_a, inputs, out_h);
    return;
  }

  int nm = 8;
  while (FIXED + (size_t)nm * PER_M > ws_size) nm >>= 1;

  char* p = (char*)d_ws;
  f16* Xh = (f16*)p;            p += 8388608;
  f16* XhT = (f16*)p;           p += 8388608;
  f16* Wh = (f16*)p;            p += 1048576;
  f16* a16 = (f16*)p;           p += 16777216;
  float* qa = (float*)p;        p += 32768;
  float* qb = (float*)p;        p += 32768;
  float* P0 = (float*)p;        p += 33554432;
  float* P1 = (float*)p;        p += 33554432;
  f16* At = (f16*)p;            p += (size_t)nm * 16777216;
  f16* Bt = (f16*)p;

  float* u1 = out_a;            // reuse out_a as u scratch (freed before softmax writes)
  float* u2 = out_a + 4194304;

  k_prep_x<<<dim3(8, 16, 8), 256, 0, stream>>>(inputs, Xh, XhT);
  k_prep_w<<<dim3(512, 2), 256, 0, stream>>>(W1, W2, Wh);
  k_gemm<0, 0><<<dim3(2, 32, 2), 512, 0, stream>>>(Xh, Wh, u1, b1, b2, 512, 512, 0, 0);

  const int chunks = 8 / nm;
  for (int cch = 0; cch < chunks; ++cch) {
    const int m0 = cch * nm + 1;
    switch (nm) {
      case 8: k_trig<8><<<8192, 256, 0, stream>>>(u1, u2, q, At, Bt, qa, qb, m0, cch == 0); break;
      case 4: k_trig<4><<<8192, 256, 0, stream>>>(u1, u2, q, At, Bt, qa, qb, m0, cch == 0); break;
      case 2: k_trig<2><<<8192, 256, 0, stream>>>(u1, u2, q, At, Bt, qa, qb, m0, cch == 0); break;
      default: k_trig<1><<<8192, 256, 0, stream>>>(u1, u2, q, At, Bt, qa, qb, m0, cch == 0); break;
    }
    const int Kloop = nm * 512;       // each z-half covers half the chunk's K
    const int ldAB = nm * 1024;
    const long halfA = (long)nm * 512;
    if (cch == 0)
      k_gemm<1, 0><<<dim3(4, 4, 16), 512, 0, stream>>>(At, Bt, P0, nullptr, nullptr,
                                                       Kloop, ldAB, halfA, 8388608L);
    else
      k_gemm<1, 1><<<dim3(4, 4, 16), 512, 0, stream>>>(At, Bt, P0, nullptr, nullptr,
                                                       Kloop, ldAB, halfA, 8388608L);
  }

  k_softmax2<<<8192, 256, 0, stream>>>(P0, P1, qa, qb, out_a, a16);
  k_gemm<2, 0><<<dim3(2, 4, 8), 512, 0, stream>>>(a16, XhT, out_h, nullptr, nullptr,
                                                  1024, 1024, 0, 0);
}